// Round 1
// 118.503 us; speedup vs baseline: 1.0410x; 1.0410x over previous
//
#include <hip/hip_runtime.h>

#define NB   2
#define SKV  1024
#define NSQ  512
#define HIN  256
#define HA   128

// projections pre-scaled by 2*log2(e):  exp2(KSC*x) = e^{2x}
// tanh(x) = 1 - 2/(e^{2x}+1)
#define KSC   2.8853900817779268f
#define LOG2E 1.4426950408889634f

// ---------------- Kernel A: projections -> exponentials ----------------
// rows [0,2048): ek[r] = exp2(KSC*(kv[r]@W_kv + b_kv)) ; rows [2048,3072): eq
// No LDS: row data is block-uniform -> scalar (s_load) path; W loads are the
// only vector traffic (coalesced dwords, L1/L2-hot).
__global__ __launch_bounds__(128) void proj_kernel(
    const float* __restrict__ kv,
    const float* __restrict__ qy,
    const float* __restrict__ Wkv,
    const float* __restrict__ bkv,
    const float* __restrict__ Wq,
    const float* __restrict__ bq,
    float* __restrict__ ek,
    float* __restrict__ eq)
{
    const int t  = threadIdx.x;            // 0..127 = output channel a
    const int r0 = blockIdx.x * 8;         // 8 rows per block
    const bool is_q = (r0 >= NB * SKV);
    const float* __restrict__ src = is_q ? (qy + (size_t)(r0 - NB * SKV) * HIN)
                                         : (kv + (size_t)r0 * HIN);
    const float* __restrict__ W  = is_q ? Wq : Wkv;
    const float* __restrict__ bs = is_q ? bq : bkv;
    float* __restrict__ dst = is_q ? (eq + (size_t)(r0 - NB * SKV) * HA)
                                   : (ek + (size_t)r0 * HA);

    float a[8];
    #pragma unroll
    for (int i = 0; i < 8; ++i) a[i] = 0.f;

    const float4* __restrict__ s4 = (const float4*)src;   // block-uniform
    #pragma unroll 2
    for (int h4 = 0; h4 < 64; ++h4) {
        float4 r[8];
        #pragma unroll
        for (int i = 0; i < 8; ++i) r[i] = s4[(size_t)i * 64 + h4];  // uniform -> s_load_dwordx4
        #pragma unroll
        for (int j = 0; j < 4; ++j) {
            const float w = W[(size_t)(h4 * 4 + j) * HA + t];        // coalesced vector load
            #pragma unroll
            for (int i = 0; i < 8; ++i)
                a[i] = fmaf(((const float*)&r[i])[j], w, a[i]);
        }
    }
    const float bb = bs[t];
    #pragma unroll
    for (int i = 0; i < 8; ++i)
        dst[(size_t)i * HA + t] = __builtin_amdgcn_exp2f((a[i] + bb) * KSC);
}

// ---------------- Kernel B: fused score/softmax/output ----------------
// one block = 4 consecutive (b,q) rows; 1024 threads (16 waves); grid 256.
// Phase 2: 1 s-row per thread; Eq/wv via block-uniform (scalar) global loads;
// paired-rcp: w0/(u)+w1/(v) = (w0*v+w1*u)*rcp(u*v)  -> 1 rcp per 2 elements.
__global__ __launch_bounds__(1024) void attn_kernel(
    const float* __restrict__ ek,          // (2048,128) = exp2(KSC*proj_kv)
    const float* __restrict__ eq,          // (1024,128) = exp2(KSC*proj_q)
    const float* __restrict__ wv,          // (128)
    const float* __restrict__ bv,          // (1)
    const float* __restrict__ kv,          // (2048,256) f32
    float* __restrict__ out)               // [262144 out0][1048576 weights]
{
    __shared__ __align__(16) float wt_s[SKV][4];      // 16 KB softmax weights
    __shared__ __align__(16) float part[16][4][HIN];  // 64 KB phase-4 partials
    __shared__ float red[2][4][16];

    const int tid  = threadIdx.x;
    const int lane = tid & 63, wid = tid >> 6;
    const int bq0  = blockIdx.x * 4;       // never straddles b (512%4==0)
    const int b    = bq0 >> 9;

    // ---- block-uniform pointers (scalar-load path) ----
    const float4* __restrict__ eq4 = (const float4*)(eq + (size_t)bq0 * HA);
    const float4* __restrict__ wv4 = (const float4*)wv;

    // ---- W0 = bv + sum(wv), computed redundantly per thread (cheap, no barrier) ----
    float W0 = bv[0];
    #pragma unroll 8
    for (int i = 0; i < 32; ++i) {
        const float4 w = wv4[i];
        W0 += (w.x + w.y) + (w.z + w.w);
    }

    // ---- phase 2: scores.  score = W0 - 2*sum_a wv_a/(Ek*Eq+1) ----
    const int s = tid;                                   // 1024 threads = 1024 s
    const float4* __restrict__ ek4 =
        (const float4*)(ek + ((size_t)(b * SKV + s)) * HA);
    float acc0 = 0.f, acc1 = 0.f, acc2 = 0.f, acc3 = 0.f;

    #pragma unroll 4
    for (int a4 = 0; a4 < 32; ++a4) {
        const float4 E = ek4[a4];                        // per-lane vector b128
        const float4 w = wv4[a4];                        // uniform -> SGPR

#define PAIR_Q(ACC, QIDX)                                                     \
        {                                                                     \
            const float4 Q = eq4[(QIDX) * 32 + a4];      /* uniform -> SGPR */\
            float u  = fmaf(E.x, Q.x, 1.f);                                   \
            float v  = fmaf(E.y, Q.y, 1.f);                                   \
            float n  = fmaf(w.x, v, w.y * u);                                 \
            ACC = fmaf(n, __builtin_amdgcn_rcpf(u * v), ACC);                 \
            float u2 = fmaf(E.z, Q.z, 1.f);                                   \
            float v2 = fmaf(E.w, Q.w, 1.f);                                   \
            float n2 = fmaf(w.z, v2, w.w * u2);                               \
            ACC = fmaf(n2, __builtin_amdgcn_rcpf(u2 * v2), ACC);              \
        }
        PAIR_Q(acc0, 0)
        PAIR_Q(acc1, 1)
        PAIR_Q(acc2, 2)
        PAIR_Q(acc3, 3)
#undef PAIR_Q
    }

    float sc[4];
    sc[0] = fmaf(-2.f, acc0, W0);
    sc[1] = fmaf(-2.f, acc1, W0);
    sc[2] = fmaf(-2.f, acc2, W0);
    sc[3] = fmaf(-2.f, acc3, W0);

    // ---- phase 3: softmax over s (block-wide, 16 waves) ----
    #pragma unroll
    for (int q = 0; q < 4; ++q) {
        float m = sc[q];
        #pragma unroll
        for (int o = 32; o > 0; o >>= 1) m = fmaxf(m, __shfl_down(m, o));
        if (lane == 0) red[0][q][wid] = m;
    }
    __syncthreads();
    float M[4];
    #pragma unroll
    for (int q = 0; q < 4; ++q) {
        float m = red[0][q][0];
        #pragma unroll
        for (int i = 1; i < 16; ++i) m = fmaxf(m, red[0][q][i]);
        M[q] = m;
    }
    float e[4];
    #pragma unroll
    for (int q = 0; q < 4; ++q) {
        e[q] = __builtin_amdgcn_exp2f((sc[q] - M[q]) * LOG2E);
        float sum = e[q];
        #pragma unroll
        for (int o = 32; o > 0; o >>= 1) sum += __shfl_down(sum, o);
        if (lane == 0) red[1][q][wid] = sum;
    }
    __syncthreads();
    float wgt[4];
    #pragma unroll
    for (int q = 0; q < 4; ++q) {
        float d = red[1][q][0];
        #pragma unroll
        for (int i = 1; i < 16; ++i) d += red[1][q][i];
        wgt[q] = e[q] * __builtin_amdgcn_rcpf(d);
    }

    float* __restrict__ outw = out + (size_t)NB * NSQ * HIN;   // weights at 262144
    *(float4*)&wt_s[s][0] = make_float4(wgt[0], wgt[1], wgt[2], wgt[3]);
    #pragma unroll
    for (int q = 0; q < 4; ++q)
        outw[(size_t)(bq0 + q) * SKV + s] = wgt[q];            // coalesced per q
    __syncthreads();

    // ---- phase 4: out[q][h] = sum_s w[q][s]*kv[b][s][h] ----
    // wave g handles s in [g*64, g*64+64); lane = float4 chunk of h
    {
        const int g = wid;                 // 0..15
        float4 ac0 = {0,0,0,0}, ac1 = {0,0,0,0}, ac2 = {0,0,0,0}, ac3 = {0,0,0,0};
        const float4* __restrict__ kvb =
            (const float4*)(kv + (size_t)(b * SKV + g * 64) * HIN);
        #pragma unroll 4
        for (int i = 0; i < 64; ++i) {
            const float4 w4 = *((const float4*)&wt_s[g * 64 + i][0]);  // LDS broadcast b128
            const float4 v  = kvb[(size_t)i * 64 + lane];              // coalesced 1KB/wave
            ac0.x = fmaf(w4.x, v.x, ac0.x); ac0.y = fmaf(w4.x, v.y, ac0.y);
            ac0.z = fmaf(w4.x, v.z, ac0.z); ac0.w = fmaf(w4.x, v.w, ac0.w);
            ac1.x = fmaf(w4.y, v.x, ac1.x); ac1.y = fmaf(w4.y, v.y, ac1.y);
            ac1.z = fmaf(w4.y, v.z, ac1.z); ac1.w = fmaf(w4.y, v.w, ac1.w);
            ac2.x = fmaf(w4.z, v.x, ac2.x); ac2.y = fmaf(w4.z, v.y, ac2.y);
            ac2.z = fmaf(w4.z, v.z, ac2.z); ac2.w = fmaf(w4.z, v.w, ac2.w);
            ac3.x = fmaf(w4.w, v.x, ac3.x); ac3.y = fmaf(w4.w, v.y, ac3.y);
            ac3.z = fmaf(w4.w, v.z, ac3.z); ac3.w = fmaf(w4.w, v.w, ac3.w);
        }
        ((float4*)part[g][0])[lane] = ac0;
        ((float4*)part[g][1])[lane] = ac1;
        ((float4*)part[g][2])[lane] = ac2;
        ((float4*)part[g][3])[lane] = ac3;
    }
    __syncthreads();
    {
        const int q = tid >> 8, h = tid & 255;           // 1024 outputs, 1/thread
        float v = 0.f;
        #pragma unroll
        for (int g2 = 0; g2 < 16; ++g2) v += part[g2][q][h];  // stride-1 banks
        out[(size_t)(bq0 + q) * HIN + h] = v;            // coalesced
    }
}

extern "C" void kernel_launch(void* const* d_in, const int* in_sizes, int n_in,
                              void* d_out, int out_size, void* d_ws, size_t ws_size,
                              hipStream_t stream) {
    (void)in_sizes; (void)n_in; (void)out_size; (void)ws_size;
    const float* kv  = (const float*)d_in[0];
    const float* qy  = (const float*)d_in[1];
    const float* Wkv = (const float*)d_in[2];
    const float* bkv = (const float*)d_in[3];
    const float* Wq  = (const float*)d_in[4];
    const float* bq  = (const float*)d_in[5];
    const float* wv  = (const float*)d_in[6];
    const float* bv  = (const float*)d_in[7];

    float* ek = (float*)d_ws;                 // 2048*128 f32 = 1 MB
    float* eqp = ek + (size_t)NB * SKV * HA;  // 1024*128 f32 = 0.5 MB
    float* out = (float*)d_out;

    hipLaunchKernelGGL(proj_kernel, dim3((NB * SKV + NB * NSQ) / 8), dim3(128), 0, stream,
                       kv, qy, Wkv, bkv, Wq, bq, ek, eqp);
    hipLaunchKernelGGL(attn_kernel, dim3(NB * NSQ / 4), dim3(1024), 0, stream,
                       ek, eqp, wv, bv, kv, out);
}

// Round 2
// 114.219 us; speedup vs baseline: 1.0800x; 1.0375x over previous
//
#include <hip/hip_runtime.h>

#define NB   2
#define SKV  1024
#define NSQ  512
#define HIN  256
#define HA   128

// projections pre-scaled by 2*log2(e):  exp2(KSC*x) = e^{2x}
// tanh(x) = 1 - 2/(e^{2x}+1); softmax is shift-invariant so the constant
// W0+bv terms of the score are dropped entirely.
#define KSC   2.8853900817779268f   // 2*log2(e)

// ---------------- Kernel A: projections -> exponentials ----------------
// kv rows -> ekT, INTERLEAVED-TRANSPOSED: ekT[b][a>>2][s][a&3] (float4 over a
// per (a4,s), s-major so attn phase-2 loads are lane-coalesced b128).
// q rows  -> eq, row-major [r][a] (attn broadcasts them from LDS).
__global__ __launch_bounds__(512) void proj_kernel(
    const float* __restrict__ kv,
    const float* __restrict__ qy,
    const float* __restrict__ Wkv,
    const float* __restrict__ bkv,
    const float* __restrict__ Wq,
    const float* __restrict__ bq,
    float* __restrict__ ekT,
    float* __restrict__ eq)
{
    __shared__ __align__(16) float rowf[8][HIN];
    const int t  = threadIdx.x;
    const int a  = t & 127;            // output channel
    const int rh = t >> 7;             // row-pair id (0..3)
    const int r0 = blockIdx.x * 8;     // 8 rows per block
    const bool is_q = (r0 >= NB * SKV);
    const float* __restrict__ src = is_q ? (qy + (size_t)(r0 - NB * SKV) * HIN)
                                         : (kv + (size_t)r0 * HIN);
    const float* __restrict__ W  = is_q ? Wq : Wkv;
    const float* __restrict__ bs = is_q ? bq : bkv;

    // stage 8 rows x 256 f32 = 512 float4, coalesced
    ((float4*)rowf)[t] = ((const float4*)src)[t];
    __syncthreads();

    float a0 = 0.f, a1 = 0.f;
    const int ra = rh * 2, rb = rh * 2 + 1;
    #pragma unroll 4
    for (int h4 = 0; h4 < 64; ++h4) {
        const float4 r4a = ((const float4*)rowf[ra])[h4];   // LDS broadcast (wave-uniform row)
        const float4 r4b = ((const float4*)rowf[rb])[h4];
        #pragma unroll
        for (int j = 0; j < 4; ++j) {
            const float w = W[(size_t)(h4 * 4 + j) * HA + a];  // coalesced, L2-hot
            a0 = fmaf(((const float*)&r4a)[j], w, a0);
            a1 = fmaf(((const float*)&r4b)[j], w, a1);
        }
    }
    const float bb = bs[a];
    const float e0 = __builtin_amdgcn_exp2f((a0 + bb) * KSC);
    const float e1 = __builtin_amdgcn_exp2f((a1 + bb) * KSC);
    if (is_q) {
        const int r = r0 - NB * SKV;
        eq[(size_t)(r + ra) * HA + a] = e0;
        eq[(size_t)(r + rb) * HA + a] = e1;
    } else {
        const int bI = r0 >> 10, s0 = r0 & 1023;
        // ekT[((bI*32 + a/4)*SKV + s)*4 + (a&3)]
        float* __restrict__ p =
            ekT + ((size_t)(bI * 32 + (a >> 2)) * SKV + s0) * 4 + (a & 3);
        p[(size_t)ra * 4] = e0;
        p[(size_t)rb * 4] = e1;
    }
}

// ---------------- Kernel B: scores + softmax + weight write ----------------
// one block = 4 consecutive (b,q) rows; 1024 threads; grid 256; thread = one s.
// score(q,s) (shifted) = -2 * sum_a wv_a / (Ek[s][a]*Eq[q][a] + 1)
// E-loads: 1 coalesced b128 per a4 (1 KB/wave-instr, L1-resident 16 KB/iter).
__global__ __launch_bounds__(1024) void attn_kernel(
    const float* __restrict__ ekT,         // interleaved-transposed exps
    const float* __restrict__ eq,          // (1024,128) exps, row-major
    const float* __restrict__ wv,          // (128)
    float* __restrict__ out)               // [262144 out0][1048576 weights]
{
    __shared__ __align__(16) float eq_s[4][HA];   // 2 KB
    __shared__ __align__(16) float wv_s[HA];      // 0.5 KB
    __shared__ float red[2][4][16];

    const int tid  = threadIdx.x;
    const int lane = tid & 63, wid = tid >> 6;
    const int bq0  = blockIdx.x * 4;       // never straddles b (512%4==0)
    const int b    = bq0 >> 9;

    if (tid < 512) ((float*)eq_s)[tid] = eq[(size_t)bq0 * HA + tid];
    else if (tid < 640) wv_s[tid - 512] = wv[tid - 512];
    __syncthreads();

    // ---- phase 2: per-thread s, 4 q accumulators; paired rcp over a ----
    const float4* __restrict__ E4 =
        (const float4*)ekT + (size_t)b * 32 * SKV + tid;   // + a4*SKV per iter
    float t0 = 0.f, t1 = 0.f, t2 = 0.f, t3 = 0.f;

    #pragma unroll 4
    for (int a4 = 0; a4 < 32; ++a4) {
        const float4 E = E4[(size_t)a4 * SKV];             // coalesced b128
        const float4 w = ((const float4*)wv_s)[a4];        // LDS broadcast

#define PQ(ACC, QI)                                                           \
        {                                                                     \
            const float4 Q = ((const float4*)eq_s[QI])[a4];  /* broadcast */  \
            float u  = fmaf(E.x, Q.x, 1.f);                                   \
            float v  = fmaf(E.y, Q.y, 1.f);                                   \
            ACC = fmaf(fmaf(w.x, v, w.y * u),                                 \
                       __builtin_amdgcn_rcpf(u * v), ACC);                    \
            float u2 = fmaf(E.z, Q.z, 1.f);                                   \
            float v2 = fmaf(E.w, Q.w, 1.f);                                   \
            ACC = fmaf(fmaf(w.z, v2, w.w * u2),                               \
                       __builtin_amdgcn_rcpf(u2 * v2), ACC);                  \
        }
        PQ(t0, 0) PQ(t1, 1) PQ(t2, 2) PQ(t3, 3)
#undef PQ
    }

    // ---- phase 3: softmax over s.  weight ∝ exp(-2*(t - tmin)) ----
    float tq[4] = {t0, t1, t2, t3};
    #pragma unroll
    for (int q = 0; q < 4; ++q) {
        float m = tq[q];
        #pragma unroll
        for (int o = 32; o > 0; o >>= 1) m = fminf(m, __shfl_down(m, o));
        if (lane == 0) red[0][q][wid] = m;
    }
    __syncthreads();
    float M[4];
    #pragma unroll
    for (int q = 0; q < 4; ++q) {
        float m = red[0][q][0];
        #pragma unroll
        for (int i = 1; i < 16; ++i) m = fminf(m, red[0][q][i]);
        M[q] = m;
    }
    float e[4];
    #pragma unroll
    for (int q = 0; q < 4; ++q) {
        e[q] = __builtin_amdgcn_exp2f((M[q] - tq[q]) * KSC);   // exp(-2(t-tmin))
        float sum = e[q];
        #pragma unroll
        for (int o = 32; o > 0; o >>= 1) sum += __shfl_down(sum, o);
        if (lane == 0) red[1][q][wid] = sum;
    }
    __syncthreads();
    float* __restrict__ outw = out + (size_t)NB * NSQ * HIN;   // weights at 262144
    #pragma unroll
    for (int q = 0; q < 4; ++q) {
        float d = red[1][q][0];
        #pragma unroll
        for (int i = 1; i < 16; ++i) d += red[1][q][i];
        outw[(size_t)(bq0 + q) * SKV + tid] = e[q] * __builtin_amdgcn_rcpf(d);
    }
}

// ---------------- Kernel C: out0 = weights @ kv ----------------
// block = (q-group of 8) x (h-half of 128); grid 256; 512 threads.
// kv L2 traffic: 256 blocks x 512 KB = 128 MB (half of the fused version).
__global__ __launch_bounds__(512) void out_kernel(
    const float* __restrict__ kv,          // (2048,256)
    const float* __restrict__ outw,        // (1024,1024) weights (just written)
    float* __restrict__ out)               // out0 (1024,256)
{
    __shared__ __align__(16) float wtT[SKV][8];        // 32 KB
    __shared__ __align__(16) float part[16][8][HA];    // 64 KB

    const int t  = threadIdx.x;
    const int qg = blockIdx.x >> 1, hh = blockIdx.x & 1;
    const int b  = qg >> 6;                // 64 q-groups per batch

    // stage 8 q-rows of weights, transposed for b128 broadcast reads
    #pragma unroll
    for (int j = 0; j < 16; ++j) {
        const int idx = j * 512 + t, q = idx >> 10, s = idx & 1023;
        wtT[s][q] = outw[(size_t)(qg * 8 + q) * SKV + s];  // coalesced read
    }
    __syncthreads();

    const int h4 = t & 31, sg = t >> 5;    // 32 float4-of-h x 16 s-groups
    const float4* __restrict__ kv4 =
        (const float4*)kv + ((size_t)(b * SKV + sg * 64)) * 64 + hh * 32 + h4;

    float4 ac[8];
    #pragma unroll
    for (int q = 0; q < 8; ++q) ac[q] = make_float4(0.f, 0.f, 0.f, 0.f);

    #pragma unroll 2
    for (int i = 0; i < 64; ++i) {
        const int s = sg * 64 + i;
        const float4 v  = kv4[(size_t)i * 64];             // coalesced 512B/half-wave
        const float4 wA = ((const float4*)wtT[s])[0];      // LDS broadcast
        const float4 wB = ((const float4*)wtT[s])[1];
        #pragma unroll
        for (int q = 0; q < 4; ++q) {
            const float wa = ((const float*)&wA)[q];
            ac[q].x = fmaf(wa, v.x, ac[q].x); ac[q].y = fmaf(wa, v.y, ac[q].y);
            ac[q].z = fmaf(wa, v.z, ac[q].z); ac[q].w = fmaf(wa, v.w, ac[q].w);
            const float wb = ((const float*)&wB)[q];
            ac[q+4].x = fmaf(wb, v.x, ac[q+4].x); ac[q+4].y = fmaf(wb, v.y, ac[q+4].y);
            ac[q+4].z = fmaf(wb, v.z, ac[q+4].z); ac[q+4].w = fmaf(wb, v.w, ac[q+4].w);
        }
    }
    #pragma unroll
    for (int q = 0; q < 8; ++q) ((float4*)part[sg][q])[h4] = ac[q];
    __syncthreads();

    #pragma unroll
    for (int k = 0; k < 2; ++k) {
        const int idx = k * 512 + t, q = idx >> 7, h = idx & 127;
        float v = 0.f;
        #pragma unroll
        for (int g = 0; g < 16; ++g) v += part[g][q][h];   // stride-1 banks
        out[(size_t)(qg * 8 + q) * HIN + hh * HA + h] = v; // coalesced
    }
}

extern "C" void kernel_launch(void* const* d_in, const int* in_sizes, int n_in,
                              void* d_out, int out_size, void* d_ws, size_t ws_size,
                              hipStream_t stream) {
    (void)in_sizes; (void)n_in; (void)out_size; (void)ws_size;
    const float* kv  = (const float*)d_in[0];
    const float* qy  = (const float*)d_in[1];
    const float* Wkv = (const float*)d_in[2];
    const float* bkv = (const float*)d_in[3];
    const float* Wq  = (const float*)d_in[4];
    const float* bq  = (const float*)d_in[5];
    const float* wv  = (const float*)d_in[6];
    float* ekT = (float*)d_ws;                 // 2*32*1024*4 f32 = 1 MB
    float* eqp = ekT + (size_t)NB * SKV * HA;  // 1024*128 f32 = 0.5 MB
    float* out = (float*)d_out;
    float* outw = out + (size_t)NB * NSQ * HIN;

    hipLaunchKernelGGL(proj_kernel, dim3((NB * SKV + NB * NSQ) / 8), dim3(512), 0, stream,
                       kv, qy, Wkv, bkv, Wq, bq, ekT, eqp);
    hipLaunchKernelGGL(attn_kernel, dim3(NB * NSQ / 4), dim3(1024), 0, stream,
                       ekT, eqp, wv, out);
    hipLaunchKernelGGL(out_kernel, dim3(NB * NSQ / 4), dim3(512), 0, stream,
                       kv, outw, out);
}